// Round 4
// baseline (164.123 us; speedup 1.0000x reference)
//
#include <hip/hip_runtime.h>
#include <math.h>

#define Bb 8
#define Cc 512
#define Nn 4096
#define Mm 64
#define OC 640            // M + M + C
#define EPSf 1e-6f

typedef unsigned short ushort_t;
typedef unsigned int uint_t;
typedef __attribute__((ext_vector_type(8))) short short8;
typedef __attribute__((ext_vector_type(4))) float f32x4;

// ---------------- workspace layout (float slots) ----------------
constexpr size_t OFF_GATE = 0;                                   // [B][C] f32
constexpr size_t OFF_BCAT = OFF_GATE + (size_t)Bb * Cc;          // [OC] f32
constexpr size_t OFF_GPM  = OFF_BCAT + (size_t)OC;               // [64][B*C] gate max partials
constexpr size_t OFF_GPS  = OFF_GPM + (size_t)64 * Bb * Cc;      // [64][B*C] gate sum partials
constexpr size_t OFF_WBF  = OFF_GPS + (size_t)64 * Bb * Cc;      // [OC][C] bf16
constexpr size_t OFF_XT   = OFF_WBF + (size_t)OC * Cc / 2;       // [B][N][C] bf16 (reused as KVpart [8][B][C][M] f32 after qkv)
constexpr size_t OFF_QBF  = OFF_XT + (size_t)Bb * Nn * Cc / 2;   // [B][M][N] bf16
constexpr size_t OFF_KBF  = OFF_QBF + (size_t)Bb * Mm * Nn / 2;  // [B][M][N] bf16
constexpr size_t OFF_VBF  = OFF_KBF + (size_t)Bb * Mm * Nn / 2;  // [B][C][N] bf16
constexpr size_t OFF_KVT  = OFF_VBF + (size_t)Bb * Cc * Nn / 2;  // [B][C][M] f32 (KV transposed)
constexpr size_t OFF_KSUM = OFF_KVT + (size_t)Bb * Cc * Mm;      // [B][M]
constexpr size_t OFF_NORM = OFF_KSUM + (size_t)Bb * Mm;          // [B][N]

__device__ __forceinline__ float softplus_f(float v) {
    return (v > 20.f) ? v : log1pf(expf(v));
}
__device__ __forceinline__ ushort_t f2bf(float f) {
    uint_t u = __float_as_uint(f);
    uint_t r = (u + 0x7fffu + ((u >> 16) & 1u)) >> 16;
    return (ushort_t)r;
}
__device__ __forceinline__ float bf2f(ushort_t h) {
    return __uint_as_float(((uint_t)h) << 16);
}
__device__ __forceinline__ void gload_lds16(const void* g, void* l) {
    __builtin_amdgcn_global_load_lds(
        (const __attribute__((address_space(1))) unsigned int*)g,
        (__attribute__((address_space(3))) unsigned int*)l, 16, 0, 0);
}
#define BARRIER()   asm volatile("s_barrier" ::: "memory")
#define WAIT_VM(N)  asm volatile("s_waitcnt vmcnt(" #N ")" ::: "memory")

// ---------------- weight concat + bf16 convert ----------------
__global__ void wconv_k(const float* __restrict__ wq, const float* __restrict__ bq,
                        const float* __restrict__ wk, const float* __restrict__ bk,
                        const float* __restrict__ wv, const float* __restrict__ bv,
                        ushort_t* __restrict__ wbf, float* __restrict__ bcat) {
    int i = blockIdx.x * 256 + threadIdx.x;
    if (i < OC * Cc) {
        int o = i / Cc, c = i % Cc;
        float v;
        if (o < Mm)            v = wq[o * Cc + c];
        else if (o < 2 * Mm)   v = wk[(o - Mm) * Cc + c];
        else                   v = wv[(o - 2 * Mm) * Cc + c];
        wbf[i] = f2bf(v);
    }
    if (i < OC) {
        float v;
        if (i < Mm)            v = bq[i];
        else if (i < 2 * Mm)   v = bk[i - Mm];
        else                   v = bv[i - 2 * Mm];
        bcat[i] = v;
    }
}

// ---------------- transpose+convert + gate partials ----------------
__global__ __launch_bounds__(256) void xtrans_k(const float* __restrict__ x, ushort_t* __restrict__ xT,
                                                float* __restrict__ gpm, float* __restrict__ gps) {
    const int nb = blockIdx.x * 64;
    const int cb = blockIdx.y * 64;
    const int b  = blockIdx.z;
    __shared__ float Xt[64][65];
    __shared__ float pmx[4][64], psm[4][64];
    const int t = threadIdx.x;
    #pragma unroll
    for (int r = 0; r < 16; r++) {
        int cl = (t >> 6) + r * 4;
        int nl = t & 63;
        Xt[cl][nl] = x[((size_t)b * Cc + cb + cl) * Nn + nb + nl];
    }
    __syncthreads();
    #pragma unroll
    for (int r = 0; r < 8; r++) {
        int nl = (t >> 5) + r * 8;
        int c0 = (t & 31) * 2;
        uint_t pk = (uint_t)f2bf(Xt[c0][nl]) | ((uint_t)f2bf(Xt[c0 + 1][nl]) << 16);
        *(uint_t*)(xT + ((size_t)b * Nn + nb + nl) * Cc + cb + c0) = pk;
    }
    {
        int cl = t & 63, q = t >> 6;
        float mx = -3.4e38f, sm = 0.f;
        #pragma unroll
        for (int j = 0; j < 16; j++) {
            float v = Xt[cl][q * 16 + j];
            mx = fmaxf(mx, v); sm += v;
        }
        pmx[q][cl] = mx; psm[q][cl] = sm;
    }
    __syncthreads();
    if (t < 64) {
        float mx = fmaxf(fmaxf(pmx[0][t], pmx[1][t]), fmaxf(pmx[2][t], pmx[3][t]));
        float sm = psm[0][t] + psm[1][t] + psm[2][t] + psm[3][t];
        size_t idx = (size_t)blockIdx.x * (Bb * Cc) + (size_t)b * Cc + cb + t;
        gpm[idx] = mx;
        gps[idx] = sm;
    }
}

// ---------------- gate reduce ----------------
__global__ void gatered_k(const float* __restrict__ gpm, const float* __restrict__ gps,
                          float* __restrict__ gate) {
    int bc = blockIdx.x;
    int l = threadIdx.x;  // 64 threads
    float mx = gpm[(size_t)l * (Bb * Cc) + bc];
    float sm = gps[(size_t)l * (Bb * Cc) + bc];
    #pragma unroll
    for (int off = 32; off; off >>= 1) {
        mx = fmaxf(mx, __shfl_xor(mx, off));
        sm += __shfl_xor(sm, off);
    }
    if (l == 0) gate[bc] = mx + sm * (1.f / Nn);
}

// ---------------- fused QKV GEMM via MFMA bf16, depth-3 counted-vmcnt pipeline ----------------
// grid: (N/128, OC/128, B), block 256 (4 waves, 2x2 of 64x64 sub-tiles), BK=32.
__global__ __launch_bounds__(256, 2) void qkv_mfma_k(const ushort_t* __restrict__ wbf,
                                                     const ushort_t* __restrict__ xT,
                                                     const float* __restrict__ bcat,
                                                     const float* __restrict__ gate,
                                                     ushort_t* __restrict__ Qbf,
                                                     ushort_t* __restrict__ Kbf,
                                                     ushort_t* __restrict__ Vbf) {
    const int nb = blockIdx.x * 128;
    const int ob = blockIdx.y * 128;
    const int b  = blockIdx.z;
    __shared__ ushort_t At[3][4096];   // [buf][o-row*32 + k]
    __shared__ ushort_t Bt[3][4096];   // [buf][n-row*32 + k]
    const int tid  = threadIdx.x;
    const int w    = tid >> 6;
    const int lane = tid & 63;
    const int wr   = w >> 1, wc = w & 1;
    const int hi   = lane >> 4, lo = lane & 15;
    const int rwl  = lane >> 2;
    const int kc   = (lane & 3) * 8;
    const ushort_t* xb = xT + (size_t)b * Nn * Cc;

    f32x4 acc[4][4] = {};

    auto stage = [&](int buf, int kb) {
        #pragma unroll
        for (int li = 0; li < 2; li++) {
            const int rw = (w * 2 + li) * 16 + rwl;
            gload_lds16(wbf + (size_t)(ob + rw) * Cc + kb + kc, &At[buf][(w * 2 + li) * 512]);
            gload_lds16(xb + (size_t)(nb + rw) * Cc + kb + kc, &Bt[buf][(w * 2 + li) * 512]);
        }
    };
    auto compute = [&](int buf) {
        short8 a[4], bfr[4];
        #pragma unroll
        for (int mi = 0; mi < 4; mi++)
            a[mi] = *(const short8*)(&At[buf][(wr * 64 + mi * 16 + lo) * 32 + hi * 8]);
        #pragma unroll
        for (int ni = 0; ni < 4; ni++)
            bfr[ni] = *(const short8*)(&Bt[buf][(wc * 64 + ni * 16 + lo) * 32 + hi * 8]);
        #pragma unroll
        for (int mi = 0; mi < 4; mi++)
            #pragma unroll
            for (int ni = 0; ni < 4; ni++)
                acc[mi][ni] = __builtin_amdgcn_mfma_f32_16x16x32_bf16(a[mi], bfr[ni], acc[mi][ni], 0, 0, 0);
    };

    stage(0, 0);
    stage(1, 32);
    #pragma unroll
    for (int t = 0; t < 16; ++t) {
        if (t + 2 < 16) stage((t + 2) % 3, (t + 2) * 32);
        if (t < 14)       { WAIT_VM(8); }
        else if (t == 14) { WAIT_VM(4); }
        else              { WAIT_VM(0); }
        BARRIER();
        compute(t % 3);
        BARRIER();
    }

    #pragma unroll
    for (int mi = 0; mi < 4; mi++) {
        #pragma unroll
        for (int r = 0; r < 4; r++) {
            const int o = ob + wr * 64 + mi * 16 + hi * 4 + r;
            const float bias = bcat[o];
            if (o < Mm) {
                ushort_t* dst = Qbf + ((size_t)b * Mm + o) * Nn;
                #pragma unroll
                for (int ni = 0; ni < 4; ni++)
                    dst[nb + wc * 64 + ni * 16 + lo] = f2bf(softplus_f(acc[mi][ni][r] + bias));
            } else if (o < 2 * Mm) {
                ushort_t* dst = Kbf + ((size_t)b * Mm + (o - Mm)) * Nn;
                #pragma unroll
                for (int ni = 0; ni < 4; ni++)
                    dst[nb + wc * 64 + ni * 16 + lo] = f2bf(softplus_f(acc[mi][ni][r] + bias));
            } else {
                const int c = o - 2 * Mm;
                const float g = gate[b * Cc + c];
                ushort_t* dst = Vbf + ((size_t)b * Cc + c) * Nn;
                #pragma unroll
                for (int ni = 0; ni < 4; ni++)
                    dst[nb + wc * 64 + ni * 16 + lo] = f2bf(g * (acc[mi][ni][r] + bias));
            }
        }
    }
}

// ---------------- Ksum[b][m] = sum_n Kbf ----------------
__global__ __launch_bounds__(256) void ksum_k(const ushort_t* __restrict__ Kbf, float* __restrict__ Ksum) {
    int bm = blockIdx.x;
    const ushort_t* row = Kbf + (size_t)bm * Nn;
    int t = threadIdx.x;
    float sm = 0.f;
    for (int i = t * 8; i < Nn; i += 2048) {
        short8 v = *(const short8*)(row + i);
        #pragma unroll
        for (int j = 0; j < 8; j++) sm += bf2f((ushort_t)v[j]);
    }
    #pragma unroll
    for (int off = 32; off; off >>= 1) sm += __shfl_xor(sm, off);
    __shared__ float ssm[4];
    if ((t & 63) == 0) ssm[t >> 6] = sm;
    __syncthreads();
    if (t == 0) Ksum[bm] = ssm[0] + ssm[1] + ssm[2] + ssm[3];
}

// ---------------- KVpart[s][b][c][m] via MFMA, depth-3 pipeline ----------------
// grid: (C/128, 8 splits, B), block 256, BK=32.
__global__ __launch_bounds__(256, 2) void kv_mfma_k(const ushort_t* __restrict__ Kbf,
                                                    const ushort_t* __restrict__ Vbf,
                                                    float* __restrict__ KVpart) {
    const int cb = blockIdx.x * 128;
    const int split = blockIdx.y;
    const int b = blockIdx.z;
    __shared__ ushort_t Vt[3][4096];
    __shared__ ushort_t Kt[3][2048];
    const int tid = threadIdx.x;
    const int w = tid >> 6, lane = tid & 63;
    const int hi = lane >> 4, lo = lane & 15;
    const int rwl = lane >> 2, kc = (lane & 3) * 8;
    const ushort_t* Vb = Vbf + (size_t)b * Cc * Nn;
    const ushort_t* Kb = Kbf + (size_t)b * Mm * Nn;
    const int nbase = split * 512;

    f32x4 acc[2][4] = {};

    auto stage = [&](int buf, int n0) {
        #pragma unroll
        for (int li = 0; li < 2; li++) {
            const int rw = (w * 2 + li) * 16 + rwl;
            gload_lds16(Vb + (size_t)(cb + rw) * Nn + n0 + kc, &Vt[buf][(w * 2 + li) * 512]);
        }
        gload_lds16(Kb + (size_t)(w * 16 + rwl) * Nn + n0 + kc, &Kt[buf][w * 512]);
    };
    auto compute = [&](int buf) {
        short8 a[2], bv[4];
        #pragma unroll
        for (int mi = 0; mi < 2; mi++)
            a[mi] = *(const short8*)(&Vt[buf][(w * 32 + mi * 16 + lo) * 32 + hi * 8]);
        #pragma unroll
        for (int ni = 0; ni < 4; ni++)
            bv[ni] = *(const short8*)(&Kt[buf][(ni * 16 + lo) * 32 + hi * 8]);
        #pragma unroll
        for (int mi = 0; mi < 2; mi++)
            #pragma unroll
            for (int ni = 0; ni < 4; ni++)
                acc[mi][ni] = __builtin_amdgcn_mfma_f32_16x16x32_bf16(a[mi], bv[ni], acc[mi][ni], 0, 0, 0);
    };

    stage(0, nbase);
    stage(1, nbase + 32);
    #pragma unroll
    for (int t = 0; t < 16; ++t) {
        if (t + 2 < 16) stage((t + 2) % 3, nbase + (t + 2) * 32);
        if (t < 14)       { WAIT_VM(6); }
        else if (t == 14) { WAIT_VM(3); }
        else              { WAIT_VM(0); }
        BARRIER();
        compute(t % 3);
        BARRIER();
    }

    float* dst = KVpart + (size_t)(split * Bb + b) * Cc * Mm;
    #pragma unroll
    for (int mi = 0; mi < 2; mi++)
        #pragma unroll
        for (int r = 0; r < 4; r++) {
            const int c = cb + w * 32 + mi * 16 + hi * 4 + r;
            #pragma unroll
            for (int ni = 0; ni < 4; ni++)
                dst[(size_t)c * Mm + ni * 16 + lo] = acc[mi][ni][r];
        }
}

// ---------------- KVT[b][c][m] = sum over 8 splits ----------------
__global__ __launch_bounds__(256) void kvred_k(const float* __restrict__ KVpart, float* __restrict__ KVT) {
    int i = blockIdx.x * 256 + threadIdx.x;  // float4 index
    const f32x4* p = (const f32x4*)KVpart;
    f32x4 s = p[i];
    #pragma unroll
    for (int sp = 1; sp < 8; sp++) s += p[(size_t)sp * 65536 + i];
    ((f32x4*)KVT)[i] = s;
}

// ---------------- norm[b][n] = 1 / sum_m Qbf[b,m,n]*(Ksum[b,m]+EPS) ----------------
__global__ __launch_bounds__(256) void norm_k(const ushort_t* __restrict__ Qbf,
                                              const float* __restrict__ Ksum,
                                              float* __restrict__ normb) {
    int b = blockIdx.y;
    int n = blockIdx.x * 256 + threadIdx.x;
    __shared__ float ks[Mm];
    if (threadIdx.x < Mm) ks[threadIdx.x] = Ksum[b * Mm + threadIdx.x] + EPSf;
    __syncthreads();
    float s = 0.f;
    #pragma unroll 8
    for (int m = 0; m < Mm; m++) s += bf2f(Qbf[((size_t)b * Mm + m) * Nn + n]) * ks[m];
    normb[(size_t)b * Nn + n] = 1.f / s;
}

// ---------------- out[b,c,n] = x + gamma * norm[b,n] * sum_m Qbf[b,m,n]*KVT[b,c,m] ----------------
__global__ __launch_bounds__(256) void final_k(const float* __restrict__ x,
                                               const ushort_t* __restrict__ Qbf,
                                               const float* __restrict__ KVT,
                                               const float* __restrict__ normb,
                                               const float* __restrict__ gamma,
                                               float* __restrict__ out) {
    const int nb = blockIdx.x * 64;
    const int cb = blockIdx.y * 64;
    const int b  = blockIdx.z;
    __shared__ float Qt[64][65];    // [m][n]
    __shared__ float KVt[64][65];   // [m][c]
    const int tid = threadIdx.x;
    const int tr = tid >> 4, tc = tid & 15;

    #pragma unroll
    for (int r = 0; r < 16; r++) {
        int a = (tid >> 6) + r * 4;   // m for Qt, c for KVt
        int bl = tid & 63;            // n for Qt, m for KVt
        Qt[a][bl]  = bf2f(Qbf[((size_t)b * Mm + a) * Nn + nb + bl]);
        KVt[bl][a] = KVT[((size_t)b * Cc + cb + a) * Mm + bl];
    }
    __syncthreads();
    float acc[4][4] = {};
    #pragma unroll 8
    for (int k = 0; k < 64; k++) {
        float a0 = KVt[k][tr * 4 + 0], a1 = KVt[k][tr * 4 + 1];
        float a2 = KVt[k][tr * 4 + 2], a3 = KVt[k][tr * 4 + 3];
        float b0 = Qt[k][tc * 4 + 0], b1 = Qt[k][tc * 4 + 1];
        float b2 = Qt[k][tc * 4 + 2], b3 = Qt[k][tc * 4 + 3];
        acc[0][0] += a0 * b0; acc[0][1] += a0 * b1; acc[0][2] += a0 * b2; acc[0][3] += a0 * b3;
        acc[1][0] += a1 * b0; acc[1][1] += a1 * b1; acc[1][2] += a1 * b2; acc[1][3] += a1 * b3;
        acc[2][0] += a2 * b0; acc[2][1] += a2 * b1; acc[2][2] += a2 * b2; acc[2][3] += a2 * b3;
        acc[3][0] += a3 * b0; acc[3][1] += a3 * b1; acc[3][2] += a3 * b2; acc[3][3] += a3 * b3;
    }
    const float g = gamma[0];
    const int n0 = nb + tc * 4;
    float4 nrm = *(const float4*)(normb + (size_t)b * Nn + n0);
    #pragma unroll
    for (int i = 0; i < 4; i++) {
        int c = cb + tr * 4 + i;
        size_t idx = ((size_t)b * Cc + c) * Nn + n0;
        float4 xv = *(const float4*)(x + idx);
        float4 o;
        o.x = xv.x + g * nrm.x * acc[i][0];
        o.y = xv.y + g * nrm.y * acc[i][1];
        o.z = xv.z + g * nrm.z * acc[i][2];
        o.w = xv.w + g * nrm.w * acc[i][3];
        *(float4*)(out + idx) = o;
    }
}

extern "C" void kernel_launch(void* const* d_in, const int* in_sizes, int n_in,
                              void* d_out, int out_size, void* d_ws, size_t ws_size,
                              hipStream_t stream) {
    const float* x     = (const float*)d_in[0];
    const float* wq    = (const float*)d_in[1];
    const float* bq    = (const float*)d_in[2];
    const float* wk    = (const float*)d_in[3];
    const float* bk    = (const float*)d_in[4];
    const float* wv    = (const float*)d_in[5];
    const float* bv    = (const float*)d_in[6];
    const float* gamma = (const float*)d_in[7];
    float* out = (float*)d_out;
    float* ws  = (float*)d_ws;

    float*    gate   = ws + OFF_GATE;
    float*    bcat   = ws + OFF_BCAT;
    float*    gpm    = ws + OFF_GPM;
    float*    gps    = ws + OFF_GPS;
    ushort_t* wbf    = (ushort_t*)(ws + OFF_WBF);
    ushort_t* xT     = (ushort_t*)(ws + OFF_XT);
    float*    KVpart = ws + OFF_XT;   // aliases xT (dead after qkv)
    ushort_t* Qbf    = (ushort_t*)(ws + OFF_QBF);
    ushort_t* Kbf    = (ushort_t*)(ws + OFF_KBF);
    ushort_t* Vbf    = (ushort_t*)(ws + OFF_VBF);
    float*    KVT    = ws + OFF_KVT;
    float*    Ksum   = ws + OFF_KSUM;
    float*    normb  = ws + OFF_NORM;

    wconv_k<<<(OC * Cc + 255) / 256, 256, 0, stream>>>(wq, bq, wk, bk, wv, bv, wbf, bcat);
    xtrans_k<<<dim3(Nn / 64, Cc / 64, Bb), 256, 0, stream>>>(x, xT, gpm, gps);
    gatered_k<<<Bb * Cc, 64, 0, stream>>>(gpm, gps, gate);
    qkv_mfma_k<<<dim3(Nn / 128, OC / 128, Bb), 256, 0, stream>>>(wbf, xT, bcat, gate, Qbf, Kbf, Vbf);
    ksum_k<<<Bb * Mm, 256, 0, stream>>>(Kbf, Ksum);
    kv_mfma_k<<<dim3(Cc / 128, 8, Bb), 256, 0, stream>>>(Kbf, Vbf, KVpart);
    kvred_k<<<(Bb * Cc * Mm / 4) / 256, 256, 0, stream>>>(KVpart, KVT);
    norm_k<<<dim3(Nn / 256, Bb), 256, 0, stream>>>(Qbf, Ksum, normb);
    final_k<<<dim3(Nn / 64, Cc / 64, Bb), 256, 0, stream>>>(x, Qbf, KVT, normb, gamma, out);
}

// Round 5
// 133.375 us; speedup vs baseline: 1.2305x; 1.2305x over previous
//
#include <hip/hip_runtime.h>
#include <math.h>

#define Bb 8
#define Cc 512
#define Nn 4096
#define Mm 64
#define OC 640            // M + M + C
#define EPSf 1e-6f

typedef unsigned short ushort_t;
typedef unsigned int uint_t;
typedef __attribute__((ext_vector_type(8))) short short8;
typedef __attribute__((ext_vector_type(4))) float f32x4;

// ---------------- workspace layout (float slots) ----------------
constexpr size_t OFF_GATE = 0;                                   // [B][C] f32
constexpr size_t OFF_BCAT = OFF_GATE + (size_t)Bb * Cc;          // [OC] f32
constexpr size_t OFF_GPM  = OFF_BCAT + (size_t)OC;               // [64][B*C] gate max partials
constexpr size_t OFF_GPS  = OFF_GPM + (size_t)64 * Bb * Cc;      // [64][B*C] gate sum partials
constexpr size_t OFF_WBF  = OFF_GPS + (size_t)64 * Bb * Cc;      // [OC][C] bf16
constexpr size_t OFF_XT   = OFF_WBF + (size_t)OC * Cc / 2;       // [B][N][C] bf16 (reused as KVpart after qkv)
constexpr size_t OFF_QBF  = OFF_XT + (size_t)Bb * Nn * Cc / 2;   // [B][M][N] bf16
constexpr size_t OFF_KBF  = OFF_QBF + (size_t)Bb * Mm * Nn / 2;  // [B][M][N] bf16
constexpr size_t OFF_VBF  = OFF_KBF + (size_t)Bb * Mm * Nn / 2;  // [B][C][N] bf16
constexpr size_t OFF_KVT  = OFF_VBF + (size_t)Bb * Cc * Nn / 2;  // [B][C][M] f32 (KV transposed)
constexpr size_t OFF_KSUM = OFF_KVT + (size_t)Bb * Cc * Mm;      // [B][M]
constexpr size_t OFF_NORM = OFF_KSUM + (size_t)Bb * Mm;          // [B][N]

// stable softplus on hw exp/log (output feeds bf16 rounding; 1e-6 rel err ok)
__device__ __forceinline__ float softplus_f(float v) {
    return fmaxf(v, 0.f) + __logf(1.f + __expf(-fabsf(v)));
}
__device__ __forceinline__ ushort_t f2bf(float f) {
    uint_t u = __float_as_uint(f);
    uint_t r = (u + 0x7fffu + ((u >> 16) & 1u)) >> 16;
    return (ushort_t)r;
}
__device__ __forceinline__ float bf2f(ushort_t h) {
    return __uint_as_float(((uint_t)h) << 16);
}
__device__ __forceinline__ void gload_lds16(const void* g, void* l) {
    __builtin_amdgcn_global_load_lds(
        (const __attribute__((address_space(1))) unsigned int*)g,
        (__attribute__((address_space(3))) unsigned int*)l, 16, 0, 0);
}
#define BARRIER()   asm volatile("s_barrier" ::: "memory")
#define WAIT_VM(N)  asm volatile("s_waitcnt vmcnt(" #N ")" ::: "memory")

// ---------------- weight concat + bf16 convert ----------------
__global__ void wconv_k(const float* __restrict__ wq, const float* __restrict__ bq,
                        const float* __restrict__ wk, const float* __restrict__ bk,
                        const float* __restrict__ wv, const float* __restrict__ bv,
                        ushort_t* __restrict__ wbf, float* __restrict__ bcat) {
    int i = blockIdx.x * 256 + threadIdx.x;
    if (i < OC * Cc) {
        int o = i / Cc, c = i % Cc;
        float v;
        if (o < Mm)            v = wq[o * Cc + c];
        else if (o < 2 * Mm)   v = wk[(o - Mm) * Cc + c];
        else                   v = wv[(o - 2 * Mm) * Cc + c];
        wbf[i] = f2bf(v);
    }
    if (i < OC) {
        float v;
        if (i < Mm)            v = bq[i];
        else if (i < 2 * Mm)   v = bk[i - Mm];
        else                   v = bv[i - 2 * Mm];
        bcat[i] = v;
    }
}

// ---------------- transpose+convert + gate partials ----------------
__global__ __launch_bounds__(256) void xtrans_k(const float* __restrict__ x, ushort_t* __restrict__ xT,
                                                float* __restrict__ gpm, float* __restrict__ gps) {
    const int nb = blockIdx.x * 64;
    const int cb = blockIdx.y * 64;
    const int b  = blockIdx.z;
    __shared__ float Xt[64][65];
    __shared__ float pmx[4][64], psm[4][64];
    const int t = threadIdx.x;
    #pragma unroll
    for (int r = 0; r < 16; r++) {
        int cl = (t >> 6) + r * 4;
        int nl = t & 63;
        Xt[cl][nl] = x[((size_t)b * Cc + cb + cl) * Nn + nb + nl];
    }
    __syncthreads();
    #pragma unroll
    for (int r = 0; r < 8; r++) {
        int nl = (t >> 5) + r * 8;
        int c0 = (t & 31) * 2;
        uint_t pk = (uint_t)f2bf(Xt[c0][nl]) | ((uint_t)f2bf(Xt[c0 + 1][nl]) << 16);
        *(uint_t*)(xT + ((size_t)b * Nn + nb + nl) * Cc + cb + c0) = pk;
    }
    {
        int cl = t & 63, q = t >> 6;
        float mx = -3.4e38f, sm = 0.f;
        #pragma unroll
        for (int j = 0; j < 16; j++) {
            float v = Xt[cl][q * 16 + j];
            mx = fmaxf(mx, v); sm += v;
        }
        pmx[q][cl] = mx; psm[q][cl] = sm;
    }
    __syncthreads();
    if (t < 64) {
        float mx = fmaxf(fmaxf(pmx[0][t], pmx[1][t]), fmaxf(pmx[2][t], pmx[3][t]));
        float sm = psm[0][t] + psm[1][t] + psm[2][t] + psm[3][t];
        size_t idx = (size_t)blockIdx.x * (Bb * Cc) + (size_t)b * Cc + cb + t;
        gpm[idx] = mx;
        gps[idx] = sm;
    }
}

// ---------------- gate reduce ----------------
__global__ void gatered_k(const float* __restrict__ gpm, const float* __restrict__ gps,
                          float* __restrict__ gate) {
    int bc = blockIdx.x;
    int l = threadIdx.x;  // 64 threads
    float mx = gpm[(size_t)l * (Bb * Cc) + bc];
    float sm = gps[(size_t)l * (Bb * Cc) + bc];
    #pragma unroll
    for (int off = 32; off; off >>= 1) {
        mx = fmaxf(mx, __shfl_xor(mx, off));
        sm += __shfl_xor(sm, off);
    }
    if (l == 0) gate[bc] = mx + sm * (1.f / Nn);
}

// ---------------- fused QKV GEMM via MFMA bf16 ----------------
// Depth-2 counted-vmcnt pipeline, XOR-swizzled LDS (slot ^= (row>>1)&3, both sides).
// grid: (N/128, OC/128, B), block 256 (4 waves, 2x2 of 64x64 sub-tiles), BK=32.
__global__ __launch_bounds__(256, 3) void qkv_mfma_k(const ushort_t* __restrict__ wbf,
                                                     const ushort_t* __restrict__ xT,
                                                     const float* __restrict__ bcat,
                                                     const float* __restrict__ gate,
                                                     ushort_t* __restrict__ Qbf,
                                                     ushort_t* __restrict__ Kbf,
                                                     ushort_t* __restrict__ Vbf) {
    const int nb = blockIdx.x * 128;
    const int ob = blockIdx.y * 128;
    const int b  = blockIdx.z;
    __shared__ ushort_t At[2][4096];   // [buf][row*32 + swz-slot*8 + e]
    __shared__ ushort_t Bt[2][4096];
    const int tid  = threadIdx.x;
    const int w    = tid >> 6;
    const int lane = tid & 63;
    const int wr   = w >> 1, wc = w & 1;
    const int hi   = lane >> 4, lo = lane & 15;
    const int rwl  = lane >> 2;
    // pre-swizzled global k-offset: lane writes physical slot (lane&3) of row (lane>>2);
    // that slot must hold k-chunk (lane&3) ^ ((row>>1)&3) = (lane&3) ^ ((lane>>3)&3)
    const int kc   = (((lane & 3) ^ ((lane >> 3) & 3)) * 8);
    // swizzled read slot for frag rows (row = base16*m + lo): slot = hi ^ ((lo>>1)&3)
    const int sx   = (hi ^ ((lo >> 1) & 3)) * 8;
    const ushort_t* xb = xT + (size_t)b * Nn * Cc;

    f32x4 acc[4][4] = {};

    auto stage = [&](int buf, int kb) {
        #pragma unroll
        for (int li = 0; li < 2; li++) {
            const int rw = (w * 2 + li) * 16 + rwl;
            gload_lds16(wbf + (size_t)(ob + rw) * Cc + kb + kc, &At[buf][(w * 2 + li) * 512]);
            gload_lds16(xb + (size_t)(nb + rw) * Cc + kb + kc, &Bt[buf][(w * 2 + li) * 512]);
        }
    };
    auto compute = [&](int buf) {
        short8 a[4], bfr[4];
        #pragma unroll
        for (int mi = 0; mi < 4; mi++)
            a[mi] = *(const short8*)(&At[buf][(wr * 64 + mi * 16 + lo) * 32 + sx]);
        #pragma unroll
        for (int ni = 0; ni < 4; ni++)
            bfr[ni] = *(const short8*)(&Bt[buf][(wc * 64 + ni * 16 + lo) * 32 + sx]);
        #pragma unroll
        for (int mi = 0; mi < 4; mi++)
            #pragma unroll
            for (int ni = 0; ni < 4; ni++)
                acc[mi][ni] = __builtin_amdgcn_mfma_f32_16x16x32_bf16(a[mi], bfr[ni], acc[mi][ni], 0, 0, 0);
    };

    stage(0, 0);
    #pragma unroll
    for (int t = 0; t < 16; ++t) {
        if (t < 15) {
            stage((t + 1) & 1, (t + 1) * 32);
            WAIT_VM(4);
        } else {
            WAIT_VM(0);
        }
        BARRIER();
        compute(t & 1);
        BARRIER();
    }

    #pragma unroll
    for (int mi = 0; mi < 4; mi++) {
        #pragma unroll
        for (int r = 0; r < 4; r++) {
            const int o = ob + wr * 64 + mi * 16 + hi * 4 + r;
            const float bias = bcat[o];
            if (o < Mm) {
                ushort_t* dst = Qbf + ((size_t)b * Mm + o) * Nn;
                #pragma unroll
                for (int ni = 0; ni < 4; ni++)
                    dst[nb + wc * 64 + ni * 16 + lo] = f2bf(softplus_f(acc[mi][ni][r] + bias));
            } else if (o < 2 * Mm) {
                ushort_t* dst = Kbf + ((size_t)b * Mm + (o - Mm)) * Nn;
                #pragma unroll
                for (int ni = 0; ni < 4; ni++)
                    dst[nb + wc * 64 + ni * 16 + lo] = f2bf(softplus_f(acc[mi][ni][r] + bias));
            } else {
                const int c = o - 2 * Mm;
                const float g = gate[b * Cc + c];
                ushort_t* dst = Vbf + ((size_t)b * Cc + c) * Nn;
                #pragma unroll
                for (int ni = 0; ni < 4; ni++)
                    dst[nb + wc * 64 + ni * 16 + lo] = f2bf(g * (acc[mi][ni][r] + bias));
            }
        }
    }
}

// ---------------- Ksum[b][m] = sum_n Kbf ----------------
__global__ __launch_bounds__(256) void ksum_k(const ushort_t* __restrict__ Kbf, float* __restrict__ Ksum) {
    int bm = blockIdx.x;
    const ushort_t* row = Kbf + (size_t)bm * Nn;
    int t = threadIdx.x;
    float sm = 0.f;
    for (int i = t * 8; i < Nn; i += 2048) {
        short8 v = *(const short8*)(row + i);
        #pragma unroll
        for (int j = 0; j < 8; j++) sm += bf2f((ushort_t)v[j]);
    }
    #pragma unroll
    for (int off = 32; off; off >>= 1) sm += __shfl_xor(sm, off);
    __shared__ float ssm[4];
    if ((t & 63) == 0) ssm[t >> 6] = sm;
    __syncthreads();
    if (t == 0) Ksum[bm] = ssm[0] + ssm[1] + ssm[2] + ssm[3];
}

// ---------------- KVpart[s][b][c][m] via MFMA, depth-2 pipeline, swizzled LDS ----------------
// grid: (C/128, 8 splits, B), block 256, BK=32.
__global__ __launch_bounds__(256, 3) void kv_mfma_k(const ushort_t* __restrict__ Kbf,
                                                    const ushort_t* __restrict__ Vbf,
                                                    float* __restrict__ KVpart) {
    const int cb = blockIdx.x * 128;
    const int split = blockIdx.y;
    const int b = blockIdx.z;
    __shared__ ushort_t Vt[2][4096];
    __shared__ ushort_t Kt[2][2048];
    const int tid = threadIdx.x;
    const int w = tid >> 6, lane = tid & 63;
    const int hi = lane >> 4, lo = lane & 15;
    const int rwl = lane >> 2;
    const int kc  = (((lane & 3) ^ ((lane >> 3) & 3)) * 8);
    const int sx  = (hi ^ ((lo >> 1) & 3)) * 8;
    const ushort_t* Vb = Vbf + (size_t)b * Cc * Nn;
    const ushort_t* Kb = Kbf + (size_t)b * Mm * Nn;
    const int nbase = split * 512;

    f32x4 acc[2][4] = {};

    auto stage = [&](int buf, int n0) {
        #pragma unroll
        for (int li = 0; li < 2; li++) {
            const int rw = (w * 2 + li) * 16 + rwl;
            gload_lds16(Vb + (size_t)(cb + rw) * Nn + n0 + kc, &Vt[buf][(w * 2 + li) * 512]);
        }
        gload_lds16(Kb + (size_t)(w * 16 + rwl) * Nn + n0 + kc, &Kt[buf][w * 512]);
    };
    auto compute = [&](int buf) {
        short8 a[2], bv[4];
        #pragma unroll
        for (int mi = 0; mi < 2; mi++)
            a[mi] = *(const short8*)(&Vt[buf][(w * 32 + mi * 16 + lo) * 32 + sx]);
        #pragma unroll
        for (int ni = 0; ni < 4; ni++)
            bv[ni] = *(const short8*)(&Kt[buf][(ni * 16 + lo) * 32 + sx]);
        #pragma unroll
        for (int mi = 0; mi < 2; mi++)
            #pragma unroll
            for (int ni = 0; ni < 4; ni++)
                acc[mi][ni] = __builtin_amdgcn_mfma_f32_16x16x32_bf16(a[mi], bv[ni], acc[mi][ni], 0, 0, 0);
    };

    stage(0, nbase);
    #pragma unroll
    for (int t = 0; t < 16; ++t) {
        if (t < 15) {
            stage((t + 1) & 1, nbase + (t + 1) * 32);
            WAIT_VM(3);
        } else {
            WAIT_VM(0);
        }
        BARRIER();
        compute(t & 1);
        BARRIER();
    }

    float* dst = KVpart + (size_t)(split * Bb + b) * Cc * Mm;
    #pragma unroll
    for (int mi = 0; mi < 2; mi++)
        #pragma unroll
        for (int r = 0; r < 4; r++) {
            const int c = cb + w * 32 + mi * 16 + hi * 4 + r;
            #pragma unroll
            for (int ni = 0; ni < 4; ni++)
                dst[(size_t)c * Mm + ni * 16 + lo] = acc[mi][ni][r];
        }
}

// ---------------- KVT[b][c][m] = sum over 8 splits ----------------
__global__ __launch_bounds__(256) void kvred_k(const float* __restrict__ KVpart, float* __restrict__ KVT) {
    int i = blockIdx.x * 256 + threadIdx.x;  // float4 index
    const f32x4* p = (const f32x4*)KVpart;
    f32x4 s = p[i];
    #pragma unroll
    for (int sp = 1; sp < 8; sp++) s += p[(size_t)sp * 65536 + i];
    ((f32x4*)KVT)[i] = s;
}

// ---------------- norm[b][n] = 1 / sum_m Qbf[b,m,n]*(Ksum[b,m]+EPS) ----------------
__global__ __launch_bounds__(256) void norm_k(const ushort_t* __restrict__ Qbf,
                                              const float* __restrict__ Ksum,
                                              float* __restrict__ normb) {
    int b = blockIdx.y;
    int n = blockIdx.x * 256 + threadIdx.x;
    __shared__ float ks[Mm];
    if (threadIdx.x < Mm) ks[threadIdx.x] = Ksum[b * Mm + threadIdx.x] + EPSf;
    __syncthreads();
    float s = 0.f;
    #pragma unroll 8
    for (int m = 0; m < Mm; m++) s += bf2f(Qbf[((size_t)b * Mm + m) * Nn + n]) * ks[m];
    normb[(size_t)b * Nn + n] = 1.f / s;
}

// ---------------- out[b,c,n] = x + gamma * norm[b,n] * sum_m Qbf[b,m,n]*KVT[b,c,m] ----------------
__global__ __launch_bounds__(256) void final_k(const float* __restrict__ x,
                                               const ushort_t* __restrict__ Qbf,
                                               const float* __restrict__ KVT,
                                               const float* __restrict__ normb,
                                               const float* __restrict__ gamma,
                                               float* __restrict__ out) {
    const int nb = blockIdx.x * 64;
    const int cb = blockIdx.y * 64;
    const int b  = blockIdx.z;
    __shared__ float Qt[64][65];    // [m][n]
    __shared__ float KVt[64][65];   // [m][c]
    const int tid = threadIdx.x;
    const int tr = tid >> 4, tc = tid & 15;

    #pragma unroll
    for (int r = 0; r < 16; r++) {
        int a = (tid >> 6) + r * 4;   // m for Qt, c for KVt
        int bl = tid & 63;            // n for Qt, m for KVt
        Qt[a][bl]  = bf2f(Qbf[((size_t)b * Mm + a) * Nn + nb + bl]);
        KVt[bl][a] = KVT[((size_t)b * Cc + cb + a) * Mm + bl];
    }
    __syncthreads();
    float acc[4][4] = {};
    #pragma unroll 8
    for (int k = 0; k < 64; k++) {
        float a0 = KVt[k][tr * 4 + 0], a1 = KVt[k][tr * 4 + 1];
        float a2 = KVt[k][tr * 4 + 2], a3 = KVt[k][tr * 4 + 3];
        float b0 = Qt[k][tc * 4 + 0], b1 = Qt[k][tc * 4 + 1];
        float b2 = Qt[k][tc * 4 + 2], b3 = Qt[k][tc * 4 + 3];
        acc[0][0] += a0 * b0; acc[0][1] += a0 * b1; acc[0][2] += a0 * b2; acc[0][3] += a0 * b3;
        acc[1][0] += a1 * b0; acc[1][1] += a1 * b1; acc[1][2] += a1 * b2; acc[1][3] += a1 * b3;
        acc[2][0] += a2 * b0; acc[2][1] += a2 * b1; acc[2][2] += a2 * b2; acc[2][3] += a2 * b3;
        acc[3][0] += a3 * b0; acc[3][1] += a3 * b1; acc[3][2] += a3 * b2; acc[3][3] += a3 * b3;
    }
    const float g = gamma[0];
    const int n0 = nb + tc * 4;
    float4 nrm = *(const float4*)(normb + (size_t)b * Nn + n0);
    #pragma unroll
    for (int i = 0; i < 4; i++) {
        int c = cb + tr * 4 + i;
        size_t idx = ((size_t)b * Cc + c) * Nn + n0;
        float4 xv = *(const float4*)(x + idx);
        float4 o;
        o.x = xv.x + g * nrm.x * acc[i][0];
        o.y = xv.y + g * nrm.y * acc[i][1];
        o.z = xv.z + g * nrm.z * acc[i][2];
        o.w = xv.w + g * nrm.w * acc[i][3];
        *(float4*)(out + idx) = o;
    }
}

extern "C" void kernel_launch(void* const* d_in, const int* in_sizes, int n_in,
                              void* d_out, int out_size, void* d_ws, size_t ws_size,
                              hipStream_t stream) {
    const float* x     = (const float*)d_in[0];
    const float* wq    = (const float*)d_in[1];
    const float* bq    = (const float*)d_in[2];
    const float* wk    = (const float*)d_in[3];
    const float* bk    = (const float*)d_in[4];
    const float* wv    = (const float*)d_in[5];
    const float* bv    = (const float*)d_in[6];
    const float* gamma = (const float*)d_in[7];
    float* out = (float*)d_out;
    float* ws  = (float*)d_ws;

    float*    gate   = ws + OFF_GATE;
    float*    bcat   = ws + OFF_BCAT;
    float*    gpm    = ws + OFF_GPM;
    float*    gps    = ws + OFF_GPS;
    ushort_t* wbf    = (ushort_t*)(ws + OFF_WBF);
    ushort_t* xT     = (ushort_t*)(ws + OFF_XT);
    float*    KVpart = ws + OFF_XT;   // aliases xT (dead after qkv)
    ushort_t* Qbf    = (ushort_t*)(ws + OFF_QBF);
    ushort_t* Kbf    = (ushort_t*)(ws + OFF_KBF);
    ushort_t* Vbf    = (ushort_t*)(ws + OFF_VBF);
    float*    KVT    = ws + OFF_KVT;
    float*    Ksum   = ws + OFF_KSUM;
    float*    normb  = ws + OFF_NORM;

    wconv_k<<<(OC * Cc + 255) / 256, 256, 0, stream>>>(wq, bq, wk, bk, wv, bv, wbf, bcat);
    xtrans_k<<<dim3(Nn / 64, Cc / 64, Bb), 256, 0, stream>>>(x, xT, gpm, gps);
    gatered_k<<<Bb * Cc, 64, 0, stream>>>(gpm, gps, gate);
    qkv_mfma_k<<<dim3(Nn / 128, OC / 128, Bb), 256, 0, stream>>>(wbf, xT, bcat, gate, Qbf, Kbf, Vbf);
    ksum_k<<<Bb * Mm, 256, 0, stream>>>(Kbf, Ksum);
    kv_mfma_k<<<dim3(Cc / 128, 8, Bb), 256, 0, stream>>>(Kbf, Vbf, KVpart);
    kvred_k<<<(Bb * Cc * Mm / 4) / 256, 256, 0, stream>>>(KVpart, KVT);
    norm_k<<<dim3(Nn / 256, Bb), 256, 0, stream>>>(Qbf, Ksum, normb);
    final_k<<<dim3(Nn / 64, Cc / 64, Bb), 256, 0, stream>>>(x, Qbf, KVT, normb, gamma, out);
}

// Round 6
// 114.239 us; speedup vs baseline: 1.4367x; 1.1675x over previous
//
#include <hip/hip_runtime.h>
#include <math.h>

#define Bb 8
#define Cc 512
#define Nn 4096
#define Mm 64
#define OC 640            // M + M + C
#define EPSf 1e-6f

typedef unsigned short ushort_t;
typedef unsigned int uint_t;
typedef __attribute__((ext_vector_type(8))) short short8;
typedef __attribute__((ext_vector_type(4))) float f32x4;

// ---------------- workspace layout (float slots) ----------------
constexpr size_t OFF_GATE = 0;                                   // [B][C] f32
constexpr size_t OFF_BCAT = OFF_GATE + (size_t)Bb * Cc;          // [OC] f32
constexpr size_t OFF_GPM  = OFF_BCAT + (size_t)OC;               // [64][B*C]
constexpr size_t OFF_GPS  = OFF_GPM + (size_t)64 * Bb * Cc;      // [64][B*C]
constexpr size_t OFF_WBF  = OFF_GPS + (size_t)64 * Bb * Cc;      // [OC][C] bf16
constexpr size_t OFF_XT   = OFF_WBF + (size_t)OC * Cc / 2;       // [B][N][C] bf16 (reused as KVpart after qkv)
constexpr size_t OFF_QBF  = OFF_XT + (size_t)Bb * Nn * Cc / 2;   // [B][M][N] bf16
constexpr size_t OFF_KBF  = OFF_QBF + (size_t)Bb * Mm * Nn / 2;  // [B][M][N] bf16
constexpr size_t OFF_VBF  = OFF_KBF + (size_t)Bb * Mm * Nn / 2;  // [B][C][N] bf16
constexpr size_t OFF_KVBF = OFF_VBF + (size_t)Bb * Cc * Nn / 2;  // [B][C][M] bf16
constexpr size_t OFF_KSUM = OFF_KVBF + (size_t)Bb * Cc * Mm / 2; // [B][M]
constexpr size_t OFF_NORM = OFF_KSUM + (size_t)Bb * Mm;          // [B][N]
constexpr size_t OFF_QT   = OFF_NORM + (size_t)Bb * Nn;          // [B][N][M] bf16

// stable softplus on hw exp/log (output feeds bf16 rounding)
__device__ __forceinline__ float softplus_f(float v) {
    return fmaxf(v, 0.f) + __logf(1.f + __expf(-fabsf(v)));
}
__device__ __forceinline__ ushort_t f2bf(float f) {
    uint_t u = __float_as_uint(f);
    uint_t r = (u + 0x7fffu + ((u >> 16) & 1u)) >> 16;
    return (ushort_t)r;
}
__device__ __forceinline__ float bf2f(ushort_t h) {
    return __uint_as_float(((uint_t)h) << 16);
}
__device__ __forceinline__ void gload_lds16(const void* g, void* l) {
    __builtin_amdgcn_global_load_lds(
        (const __attribute__((address_space(1))) unsigned int*)g,
        (__attribute__((address_space(3))) unsigned int*)l, 16, 0, 0);
}
#define BARRIER()   asm volatile("s_barrier" ::: "memory")
#define WAIT_VM(N)  asm volatile("s_waitcnt vmcnt(" #N ")" ::: "memory")

// ---------------- weight concat + bf16 convert ----------------
__global__ void wconv_k(const float* __restrict__ wq, const float* __restrict__ bq,
                        const float* __restrict__ wk, const float* __restrict__ bk,
                        const float* __restrict__ wv, const float* __restrict__ bv,
                        ushort_t* __restrict__ wbf, float* __restrict__ bcat) {
    int i = blockIdx.x * 256 + threadIdx.x;
    if (i < OC * Cc) {
        int o = i / Cc, c = i % Cc;
        float v;
        if (o < Mm)            v = wq[o * Cc + c];
        else if (o < 2 * Mm)   v = wk[(o - Mm) * Cc + c];
        else                   v = wv[(o - 2 * Mm) * Cc + c];
        wbf[i] = f2bf(v);
    }
    if (i < OC) {
        float v;
        if (i < Mm)            v = bq[i];
        else if (i < 2 * Mm)   v = bk[i - Mm];
        else                   v = bv[i - 2 * Mm];
        bcat[i] = v;
    }
}

// ---------------- transpose+convert + gate partials ----------------
__global__ __launch_bounds__(256) void xtrans_k(const float* __restrict__ x, ushort_t* __restrict__ xT,
                                                float* __restrict__ gpm, float* __restrict__ gps) {
    const int nb = blockIdx.x * 64;
    const int cb = blockIdx.y * 64;
    const int b  = blockIdx.z;
    __shared__ float Xt[64][65];
    __shared__ float pmx[4][64], psm[4][64];
    const int t = threadIdx.x;
    #pragma unroll
    for (int r = 0; r < 16; r++) {
        int cl = (t >> 6) + r * 4;
        int nl = t & 63;
        Xt[cl][nl] = x[((size_t)b * Cc + cb + cl) * Nn + nb + nl];
    }
    __syncthreads();
    #pragma unroll
    for (int r = 0; r < 8; r++) {
        int nl = (t >> 5) + r * 8;
        int c0 = (t & 31) * 2;
        uint_t pk = (uint_t)f2bf(Xt[c0][nl]) | ((uint_t)f2bf(Xt[c0 + 1][nl]) << 16);
        *(uint_t*)(xT + ((size_t)b * Nn + nb + nl) * Cc + cb + c0) = pk;
    }
    {
        int cl = t & 63, q = t >> 6;
        float mx = -3.4e38f, sm = 0.f;
        #pragma unroll
        for (int j = 0; j < 16; j++) {
            float v = Xt[cl][q * 16 + j];
            mx = fmaxf(mx, v); sm += v;
        }
        pmx[q][cl] = mx; psm[q][cl] = sm;
    }
    __syncthreads();
    if (t < 64) {
        float mx = fmaxf(fmaxf(pmx[0][t], pmx[1][t]), fmaxf(pmx[2][t], pmx[3][t]));
        float sm = psm[0][t] + psm[1][t] + psm[2][t] + psm[3][t];
        size_t idx = (size_t)blockIdx.x * (Bb * Cc) + (size_t)b * Cc + cb + t;
        gpm[idx] = mx;
        gps[idx] = sm;
    }
}

// ---------------- gate reduce ----------------
__global__ void gatered_k(const float* __restrict__ gpm, const float* __restrict__ gps,
                          float* __restrict__ gate) {
    int bc = blockIdx.x;
    int l = threadIdx.x;  // 64 threads
    float mx = gpm[(size_t)l * (Bb * Cc) + bc];
    float sm = gps[(size_t)l * (Bb * Cc) + bc];
    #pragma unroll
    for (int off = 32; off; off >>= 1) {
        mx = fmaxf(mx, __shfl_xor(mx, off));
        sm += __shfl_xor(sm, off);
    }
    if (l == 0) gate[bc] = mx + sm * (1.f / Nn);
}

// ---------------- fused QKV GEMM via MFMA bf16 ----------------
// Depth-2 counted-vmcnt pipeline, XOR-swizzled LDS (4 slots/row of 32 elems).
__global__ __launch_bounds__(256, 3) void qkv_mfma_k(const ushort_t* __restrict__ wbf,
                                                     const ushort_t* __restrict__ xT,
                                                     const float* __restrict__ bcat,
                                                     const float* __restrict__ gate,
                                                     ushort_t* __restrict__ Qbf,
                                                     ushort_t* __restrict__ Kbf,
                                                     ushort_t* __restrict__ Vbf) {
    const int nb = blockIdx.x * 128;
    const int ob = blockIdx.y * 128;
    const int b  = blockIdx.z;
    __shared__ ushort_t At[2][4096];
    __shared__ ushort_t Bt[2][4096];
    const int tid  = threadIdx.x;
    const int w    = tid >> 6;
    const int lane = tid & 63;
    const int wr   = w >> 1, wc = w & 1;
    const int hi   = lane >> 4, lo = lane & 15;
    const int rwl  = lane >> 2;
    const int kc   = (((lane & 3) ^ ((lane >> 3) & 3)) * 8);
    const int sx   = (hi ^ ((lo >> 1) & 3)) * 8;
    const ushort_t* xb = xT + (size_t)b * Nn * Cc;

    f32x4 acc[4][4] = {};

    auto stage = [&](int buf, int kb) {
        #pragma unroll
        for (int li = 0; li < 2; li++) {
            const int rw = (w * 2 + li) * 16 + rwl;
            gload_lds16(wbf + (size_t)(ob + rw) * Cc + kb + kc, &At[buf][(w * 2 + li) * 512]);
            gload_lds16(xb + (size_t)(nb + rw) * Cc + kb + kc, &Bt[buf][(w * 2 + li) * 512]);
        }
    };
    auto compute = [&](int buf) {
        short8 a[4], bfr[4];
        #pragma unroll
        for (int mi = 0; mi < 4; mi++)
            a[mi] = *(const short8*)(&At[buf][(wr * 64 + mi * 16 + lo) * 32 + sx]);
        #pragma unroll
        for (int ni = 0; ni < 4; ni++)
            bfr[ni] = *(const short8*)(&Bt[buf][(wc * 64 + ni * 16 + lo) * 32 + sx]);
        #pragma unroll
        for (int mi = 0; mi < 4; mi++)
            #pragma unroll
            for (int ni = 0; ni < 4; ni++)
                acc[mi][ni] = __builtin_amdgcn_mfma_f32_16x16x32_bf16(a[mi], bfr[ni], acc[mi][ni], 0, 0, 0);
    };

    stage(0, 0);
    #pragma unroll
    for (int t = 0; t < 16; ++t) {
        if (t < 15) {
            stage((t + 1) & 1, (t + 1) * 32);
            WAIT_VM(4);
        } else {
            WAIT_VM(0);
        }
        BARRIER();
        compute(t & 1);
        BARRIER();
    }

    #pragma unroll
    for (int mi = 0; mi < 4; mi++) {
        #pragma unroll
        for (int r = 0; r < 4; r++) {
            const int o = ob + wr * 64 + mi * 16 + hi * 4 + r;
            const float bias = bcat[o];
            if (o < Mm) {
                ushort_t* dst = Qbf + ((size_t)b * Mm + o) * Nn;
                #pragma unroll
                for (int ni = 0; ni < 4; ni++)
                    dst[nb + wc * 64 + ni * 16 + lo] = f2bf(softplus_f(acc[mi][ni][r] + bias));
            } else if (o < 2 * Mm) {
                ushort_t* dst = Kbf + ((size_t)b * Mm + (o - Mm)) * Nn;
                #pragma unroll
                for (int ni = 0; ni < 4; ni++)
                    dst[nb + wc * 64 + ni * 16 + lo] = f2bf(softplus_f(acc[mi][ni][r] + bias));
            } else {
                const int c = o - 2 * Mm;
                const float g = gate[b * Cc + c];
                ushort_t* dst = Vbf + ((size_t)b * Cc + c) * Nn;
                #pragma unroll
                for (int ni = 0; ni < 4; ni++)
                    dst[nb + wc * 64 + ni * 16 + lo] = f2bf(g * (acc[mi][ni][r] + bias));
            }
        }
    }
}

// ---------------- Ksum[b][m] = sum_n Kbf ----------------
__global__ __launch_bounds__(256) void ksum_k(const ushort_t* __restrict__ Kbf, float* __restrict__ Ksum) {
    int bm = blockIdx.x;
    const ushort_t* row = Kbf + (size_t)bm * Nn;
    int t = threadIdx.x;
    float sm = 0.f;
    for (int i = t * 8; i < Nn; i += 2048) {
        short8 v = *(const short8*)(row + i);
        #pragma unroll
        for (int j = 0; j < 8; j++) sm += bf2f((ushort_t)v[j]);
    }
    #pragma unroll
    for (int off = 32; off; off >>= 1) sm += __shfl_xor(sm, off);
    __shared__ float ssm[4];
    if ((t & 63) == 0) ssm[t >> 6] = sm;
    __syncthreads();
    if (t == 0) Ksum[bm] = ssm[0] + ssm[1] + ssm[2] + ssm[3];
}

// ---------------- KVpart[s][b][c][m] via MFMA, depth-2 pipeline, swizzled LDS ----------------
__global__ __launch_bounds__(256, 3) void kv_mfma_k(const ushort_t* __restrict__ Kbf,
                                                    const ushort_t* __restrict__ Vbf,
                                                    float* __restrict__ KVpart) {
    const int cb = blockIdx.x * 128;
    const int split = blockIdx.y;
    const int b = blockIdx.z;
    __shared__ ushort_t Vt[2][4096];
    __shared__ ushort_t Kt[2][2048];
    const int tid = threadIdx.x;
    const int w = tid >> 6, lane = tid & 63;
    const int hi = lane >> 4, lo = lane & 15;
    const int rwl = lane >> 2;
    const int kc  = (((lane & 3) ^ ((lane >> 3) & 3)) * 8);
    const int sx  = (hi ^ ((lo >> 1) & 3)) * 8;
    const ushort_t* Vb = Vbf + (size_t)b * Cc * Nn;
    const ushort_t* Kb = Kbf + (size_t)b * Mm * Nn;
    const int nbase = split * 512;

    f32x4 acc[2][4] = {};

    auto stage = [&](int buf, int n0) {
        #pragma unroll
        for (int li = 0; li < 2; li++) {
            const int rw = (w * 2 + li) * 16 + rwl;
            gload_lds16(Vb + (size_t)(cb + rw) * Nn + n0 + kc, &Vt[buf][(w * 2 + li) * 512]);
        }
        gload_lds16(Kb + (size_t)(w * 16 + rwl) * Nn + n0 + kc, &Kt[buf][w * 512]);
    };
    auto compute = [&](int buf) {
        short8 a[2], bv[4];
        #pragma unroll
        for (int mi = 0; mi < 2; mi++)
            a[mi] = *(const short8*)(&Vt[buf][(w * 32 + mi * 16 + lo) * 32 + sx]);
        #pragma unroll
        for (int ni = 0; ni < 4; ni++)
            bv[ni] = *(const short8*)(&Kt[buf][(ni * 16 + lo) * 32 + sx]);
        #pragma unroll
        for (int mi = 0; mi < 2; mi++)
            #pragma unroll
            for (int ni = 0; ni < 4; ni++)
                acc[mi][ni] = __builtin_amdgcn_mfma_f32_16x16x32_bf16(a[mi], bv[ni], acc[mi][ni], 0, 0, 0);
    };

    stage(0, nbase);
    #pragma unroll
    for (int t = 0; t < 16; ++t) {
        if (t < 15) {
            stage((t + 1) & 1, nbase + (t + 1) * 32);
            WAIT_VM(3);
        } else {
            WAIT_VM(0);
        }
        BARRIER();
        compute(t & 1);
        BARRIER();
    }

    float* dst = KVpart + (size_t)(split * Bb + b) * Cc * Mm;
    #pragma unroll
    for (int mi = 0; mi < 2; mi++)
        #pragma unroll
        for (int r = 0; r < 4; r++) {
            const int c = cb + w * 32 + mi * 16 + hi * 4 + r;
            #pragma unroll
            for (int ni = 0; ni < 4; ni++)
                dst[(size_t)c * Mm + ni * 16 + lo] = acc[mi][ni][r];
        }
}

// ---------------- KVbf[b][c][m] = bf16(sum over 8 splits) ----------------
__global__ __launch_bounds__(256) void kvred_k(const float* __restrict__ KVpart, ushort_t* __restrict__ KVbf) {
    int i = blockIdx.x * 256 + threadIdx.x;  // float4 group index; total B*C*M/4 = 65536
    const f32x4* p = (const f32x4*)KVpart;
    f32x4 s = p[i];
    #pragma unroll
    for (int sp = 1; sp < 8; sp++) s += p[(size_t)sp * 65536 + i];
    uint2 pk;
    pk.x = (uint_t)f2bf(s[0]) | ((uint_t)f2bf(s[1]) << 16);
    pk.y = (uint_t)f2bf(s[2]) | ((uint_t)f2bf(s[3]) << 16);
    *(uint2*)(KVbf + (size_t)i * 4) = pk;
}

// ---------------- Q transpose + norm: QT[b][n][m] = Qbf[b][m][n]; norm = 1/sum_m Q*ks ----------------
// grid: (N/64, B), block 256
__global__ __launch_bounds__(256) void qtransnorm_k(const ushort_t* __restrict__ Qbf,
                                                    const float* __restrict__ Ksum,
                                                    ushort_t* __restrict__ QT,
                                                    float* __restrict__ normb) {
    const int n0 = blockIdx.x * 64;
    const int b  = blockIdx.y;
    __shared__ float Qs[64][65];
    __shared__ float ks[64];
    __shared__ float ps[4][64];
    const int t = threadIdx.x;
    if (t < 64) ks[t] = Ksum[b * Mm + t] + EPSf;
    {
        int m = t >> 2, q = t & 3;
        const ushort_t* src = Qbf + ((size_t)b * Mm + m) * Nn + n0 + q * 16;
        short8 v0 = *(const short8*)(src);
        short8 v1 = *(const short8*)(src + 8);
        #pragma unroll
        for (int j = 0; j < 8; j++) {
            Qs[m][q * 16 + j]     = bf2f((ushort_t)v0[j]);
            Qs[m][q * 16 + 8 + j] = bf2f((ushort_t)v1[j]);
        }
    }
    __syncthreads();
    {
        int n = t & 63, ch = t >> 6;
        float s = 0.f;
        #pragma unroll
        for (int j = 0; j < 16; j++) s += Qs[ch * 16 + j][n] * ks[ch * 16 + j];
        ps[ch][n] = s;
    }
    __syncthreads();
    if (t < 64) normb[(size_t)b * Nn + n0 + t] = 1.f / (ps[0][t] + ps[1][t] + ps[2][t] + ps[3][t]);
    #pragma unroll
    for (int i = 0; i < 2; i++) {
        int u = t + i * 256;
        int n = u >> 3, j = u & 7;
        short8 v;
        #pragma unroll
        for (int jj = 0; jj < 8; jj++) v[jj] = (short)f2bf(Qs[j * 8 + jj][n]);
        *(short8*)(QT + ((size_t)b * Nn + n0 + n) * Mm + j * 8) = v;
    }
}

// ---------------- final: out[b,c,n] = x + gamma*norm[n]*sum_m QT[n,m]*KVbf[c,m] via MFMA ----------------
// grid: (N/128, C/128, B), block 256 (4 waves, wr->n-half, wc->c-half), K=64 single stage.
__global__ __launch_bounds__(256, 2) void final_mfma_k(const float* __restrict__ x,
                                                       const ushort_t* __restrict__ QT,
                                                       const ushort_t* __restrict__ KVbf,
                                                       const float* __restrict__ normb,
                                                       const float* __restrict__ gamma,
                                                       float* __restrict__ out) {
    const int nb = blockIdx.x * 128;
    const int cb = blockIdx.y * 128;
    const int b  = blockIdx.z;
    __shared__ ushort_t Qs[128 * 64];   // [n-row][m], 8 16B-slots/row, XOR-swizzled
    __shared__ ushort_t Ks[128 * 64];   // [c-row][m]
    const int tid  = threadIdx.x;
    const int w    = tid >> 6;
    const int lane = tid & 63;
    const int wr   = w >> 1, wc = w & 1;
    const int hi   = lane >> 4, lo = lane & 15;
    const int lr   = lane >> 3;
    // pre-swizzled source: lane fills physical slot (lane&7) of row (lane>>3);
    // logical slot there = (lane&7) ^ ((lane>>3)&7)
    const int swz  = (((lane & 7) ^ (lr & 7)) * 8);
    const ushort_t* Qb = QT + (size_t)b * Nn * Mm;
    const ushort_t* Kb = KVbf + (size_t)b * Cc * Mm;

    #pragma unroll
    for (int p = 0; p < 4; p++) {
        const int rb = p * 32 + w * 8;
        gload_lds16(Qb + (size_t)(nb + rb + lr) * Mm + swz, &Qs[rb * 64]);
        gload_lds16(Kb + (size_t)(cb + rb + lr) * Mm + swz, &Ks[rb * 64]);
    }
    __syncthreads();

    f32x4 acc[4][4] = {};
    #pragma unroll
    for (int kk = 0; kk < 2; kk++) {
        short8 a[4], bfr[4];
        #pragma unroll
        for (int mi = 0; mi < 4; mi++) {
            const int row = wr * 64 + mi * 16 + lo;
            a[mi] = *(const short8*)(&Qs[row * 64 + (((kk * 4 + hi) ^ (lo & 7)) * 8)]);
        }
        #pragma unroll
        for (int ni = 0; ni < 4; ni++) {
            const int row = wc * 64 + ni * 16 + lo;
            bfr[ni] = *(const short8*)(&Ks[row * 64 + (((kk * 4 + hi) ^ (lo & 7)) * 8)]);
        }
        #pragma unroll
        for (int mi = 0; mi < 4; mi++)
            #pragma unroll
            for (int ni = 0; ni < 4; ni++)
                acc[mi][ni] = __builtin_amdgcn_mfma_f32_16x16x32_bf16(a[mi], bfr[ni], acc[mi][ni], 0, 0, 0);
    }

    const float g = gamma[0];
    #pragma unroll
    for (int mi = 0; mi < 4; mi++) {
        const int n0 = nb + wr * 64 + mi * 16 + hi * 4;
        float4 nrm = *(const float4*)(normb + (size_t)b * Nn + n0);
        #pragma unroll
        for (int ni = 0; ni < 4; ni++) {
            const int c = cb + wc * 64 + ni * 16 + lo;
            size_t idx = ((size_t)b * Cc + c) * Nn + n0;
            float4 xv = *(const float4*)(x + idx);
            float4 o;
            o.x = xv.x + g * nrm.x * acc[mi][ni][0];
            o.y = xv.y + g * nrm.y * acc[mi][ni][1];
            o.z = xv.z + g * nrm.z * acc[mi][ni][2];
            o.w = xv.w + g * nrm.w * acc[mi][ni][3];
            *(float4*)(out + idx) = o;
        }
    }
}

extern "C" void kernel_launch(void* const* d_in, const int* in_sizes, int n_in,
                              void* d_out, int out_size, void* d_ws, size_t ws_size,
                              hipStream_t stream) {
    const float* x     = (const float*)d_in[0];
    const float* wq    = (const float*)d_in[1];
    const float* bq    = (const float*)d_in[2];
    const float* wk    = (const float*)d_in[3];
    const float* bk    = (const float*)d_in[4];
    const float* wv    = (const float*)d_in[5];
    const float* bv    = (const float*)d_in[6];
    const float* gamma = (const float*)d_in[7];
    float* out = (float*)d_out;
    float* ws  = (float*)d_ws;

    float*    gate   = ws + OFF_GATE;
    float*    bcat   = ws + OFF_BCAT;
    float*    gpm    = ws + OFF_GPM;
    float*    gps    = ws + OFF_GPS;
    ushort_t* wbf    = (ushort_t*)(ws + OFF_WBF);
    ushort_t* xT     = (ushort_t*)(ws + OFF_XT);
    float*    KVpart = ws + OFF_XT;   // aliases xT (dead after qkv)
    ushort_t* Qbf    = (ushort_t*)(ws + OFF_QBF);
    ushort_t* Kbf    = (ushort_t*)(ws + OFF_KBF);
    ushort_t* Vbf    = (ushort_t*)(ws + OFF_VBF);
    ushort_t* KVbf   = (ushort_t*)(ws + OFF_KVBF);
    float*    Ksum   = ws + OFF_KSUM;
    float*    normb  = ws + OFF_NORM;
    ushort_t* QT     = (ushort_t*)(ws + OFF_QT);

    wconv_k<<<(OC * Cc + 255) / 256, 256, 0, stream>>>(wq, bq, wk, bk, wv, bv, wbf, bcat);
    xtrans_k<<<dim3(Nn / 64, Cc / 64, Bb), 256, 0, stream>>>(x, xT, gpm, gps);
    gatered_k<<<Bb * Cc, 64, 0, stream>>>(gpm, gps, gate);
    qkv_mfma_k<<<dim3(Nn / 128, OC / 128, Bb), 256, 0, stream>>>(wbf, xT, bcat, gate, Qbf, Kbf, Vbf);
    ksum_k<<<Bb * Mm, 256, 0, stream>>>(Kbf, Ksum);
    kv_mfma_k<<<dim3(Cc / 128, 8, Bb), 256, 0, stream>>>(Kbf, Vbf, KVpart);
    kvred_k<<<(Bb * Cc * Mm / 4) / 256, 256, 0, stream>>>(KVpart, KVbf);
    qtransnorm_k<<<dim3(Nn / 64, Bb), 256, 0, stream>>>(Qbf, Ksum, QT, normb);
    final_mfma_k<<<dim3(Nn / 128, Cc / 128, Bb), 256, 0, stream>>>(x, QT, KVbf, normb, gamma, out);
}